// Round 1
// 1757.131 us; speedup vs baseline: 1.0024x; 1.0024x over previous
//
#include <hip/hip_runtime.h>
#include <cstdint>
#include <cstddef>

#define Bsz 32
#define Nn 1024
#define Dd 768
#define NE_TOK 4
#define NE 8
#define HN 4096
#define HD 3072
#define INTER_ELEMS (768 * 4096)  /* == 1024*3072, per-pair intermediate */
#define CHUNK 16

typedef __bf16 bf16x8 __attribute__((ext_vector_type(8)));
typedef float f32x4 __attribute__((ext_vector_type(4)));
typedef unsigned int __attribute__((address_space(1))) as1_uint;
typedef unsigned int __attribute__((address_space(3))) as3_uint;

__device__ __forceinline__ unsigned short f2bf(float f) {
  union { float f; unsigned u; } c; c.f = f;
  unsigned u = c.u;
  u += 0x7fffu + ((u >> 16) & 1u);   // RNE
  return (unsigned short)(u >> 16);
}

__device__ __forceinline__ float gelu_f(float x) {
  float t = tanhf(0.7978845608028654f * (x + 0.044715f * x * x * x));
  return 0.5f * x * (1.0f + t);
}

__device__ __forceinline__ void async_cp16(const unsigned short* g, unsigned short* l) {
  __builtin_amdgcn_global_load_lds((as1_uint*)(void*)g, (as3_uint*)(void*)l, 16, 0, 0);
}

// ---------------- core 128x128 bf16 GEMM tile: C = A (M x K) * B^T (N x K) ----------------
// A, B row-major, K contiguous. 256 threads, 4 waves, each wave owns a 64x64 quadrant as
// 4x4 MFMA 16x16x32 fragments. Double-buffered LDS: stage K-step t+1 BEFORE computing t
// (vmcnt(0) drain at the barrier then lands AFTER the MFMAs -> staging latency hidden).
// LDS layout is chunk-swizzled: granule (row, cc) lives at slot row*4 + (cc ^ ((row>>1)&3)),
// realized by pre-swizzling the per-lane GLOBAL source (global_load_lds dest is linear) and
// applying the same XOR on the read side -> ds_read_b128 goes 8-way -> 2-way (free).
__device__ __forceinline__ void gemm_core(const unsigned short* Ag, const unsigned short* Bg,
                                          int K, int tm, int tn,
                                          unsigned short* sA, unsigned short* sB,
                                          f32x4 acc[4][4]) {
  const int tid = threadIdx.x;
  const int wave = tid >> 6;
  const int lane = tid & 63;
  const int wr = (wave >> 1) * 64;
  const int wc = (wave & 1) * 64;

  f32x4 zero = {0.f, 0.f, 0.f, 0.f};
#pragma unroll
  for (int i = 0; i < 4; ++i)
#pragma unroll
    for (int j = 0; j < 4; ++j) acc[i][j] = zero;

  // staging: one buffer is 128 rows x 32 cols bf16 = 8KB = 8 wave-calls of 1KB.
  // chunk c = q*64 + lane -> row = c>>2, chunk-in-row swizzled: cc_global = (c ^ (c>>3)) & 3
  const int q0 = wave * 2, q1 = wave * 2 + 1;
  const int c0 = q0 * 64 + lane, c1 = q1 * 64 + lane;
  const int ar0 = c0 >> 2, as0 = ((c0 ^ (c0 >> 3)) & 3) * 8;
  const int ar1 = c1 >> 2, as1 = ((c1 ^ (c1 >> 3)) & 3) * 8;
  const unsigned short* Ag0 = Ag + (size_t)(tm * 128 + ar0) * K + as0;
  const unsigned short* Ag1 = Ag + (size_t)(tm * 128 + ar1) * K + as1;
  const unsigned short* Bg0 = Bg + (size_t)(tn * 128 + ar0) * K + as0;
  const unsigned short* Bg1 = Bg + (size_t)(tn * 128 + ar1) * K + as1;
  unsigned short* sA0 = sA + q0 * 512;
  unsigned short* sA1 = sA + q1 * 512;
  unsigned short* sB0 = sB + q0 * 512;
  unsigned short* sB1 = sB + q1 * 512;

  // fragment read offset: row = wr + i*16 + (lane&15), chunk = lane>>4, same XOR swizzle
  const int swz = ((lane >> 4) ^ (lane >> 1)) & 3;
  const int fro = (lane & 15) * 32 + swz * 8;

  // prologue: stage K-step 0 into buffer 0
  async_cp16(Ag0, sA0);
  async_cp16(Ag1, sA1);
  async_cp16(Bg0, sB0);
  async_cp16(Bg1, sB1);
  __syncthreads();

  int cur = 0;
  for (int k0 = 0; k0 < K; k0 += 32) {
    const int k1 = k0 + 32;
    if (k1 < K) {  // issue next K-step's staging first (prefetch into other buffer)
      const int nb = (cur ^ 1) * 4096;
      async_cp16(Ag0 + k1, sA0 + nb);
      async_cp16(Ag1 + k1, sA1 + nb);
      async_cp16(Bg0 + k1, sB0 + nb);
      async_cp16(Bg1 + k1, sB1 + nb);
    }
    const unsigned short* pA = sA + cur * 4096;
    const unsigned short* pB = sB + cur * 4096;
    bf16x8 a[4], bb[4];
#pragma unroll
    for (int i = 0; i < 4; ++i)
      a[i] = *(const bf16x8*)(pA + (wr + i * 16) * 32 + fro);
#pragma unroll
    for (int j = 0; j < 4; ++j)
      bb[j] = *(const bf16x8*)(pB + (wc + j * 16) * 32 + fro);
#pragma unroll
    for (int i = 0; i < 4; ++i)
#pragma unroll
      for (int j = 0; j < 4; ++j)
        acc[i][j] = __builtin_amdgcn_mfma_f32_16x16x32_bf16(a[i], bb[j], acc[i][j], 0, 0, 0);
    // single barrier per K-step: drains this step's prefetch (after MFMAs) and
    // guarantees all waves are done reading buffer `cur` before it is overwritten.
    __syncthreads();
    cur ^= 1;
  }
}

// ---------------- prep kernels ----------------

__global__ void mean_kernel(const float* __restrict__ x, float* __restrict__ xmean) {
  int idx = blockIdx.x * 256 + threadIdx.x;  // B*D = 24576 threads
  int b = idx / Dd, d = idx - b * Dd;
  const float* p = x + (size_t)b * Nn * Dd + d;
  float s = 0.f;
#pragma unroll 8
  for (int n = 0; n < Nn; ++n) s += p[(size_t)n * Dd];
  xmean[idx] = s * (1.0f / Nn);
}

__global__ void router_kernel(const float* __restrict__ xmean, const float* __restrict__ rw,
                              int* __restrict__ topi, float* __restrict__ topw,
                              float* __restrict__ aux_out) {
  __shared__ float probs[Bsz][NE];
  __shared__ int top1[Bsz];
  int t = threadIdx.x;
  for (int p = t; p < Bsz * NE; p += 64) {
    int b = p >> 3, e = p & 7;
    const float* xm = xmean + b * Dd;
    const float* w = rw + e * Dd;
    float s = 0.f;
    for (int i = 0; i < Dd; ++i) s += xm[i] * w[i];
    probs[b][e] = s;  // logits for now
  }
  __syncthreads();
  if (t < Bsz) {
    float mx = -1e30f;
    for (int e = 0; e < NE; ++e) mx = fmaxf(mx, probs[t][e]);
    float pe[NE]; float sum = 0.f;
    for (int e = 0; e < NE; ++e) { pe[e] = expf(probs[t][e] - mx); sum += pe[e]; }
    float inv = 1.f / sum;
    for (int e = 0; e < NE; ++e) { pe[e] *= inv; probs[t][e] = pe[e]; }
    int i0 = 0;
    for (int e = 1; e < NE; ++e) if (pe[e] > pe[i0]) i0 = e;   // ties -> lowest idx (jax)
    int i1 = (i0 == 0) ? 1 : 0;
    for (int e = 0; e < NE; ++e) if (e != i0 && pe[e] > pe[i1]) i1 = e;
    float ws2 = pe[i0] + pe[i1];
    topi[t * 2] = i0; topi[t * 2 + 1] = i1;
    topw[t * 2] = pe[i0] / ws2; topw[t * 2 + 1] = pe[i1] / ws2;
    top1[t] = i0;
  }
  __syncthreads();
  if (t == 0) {
    float aux = 0.f;
    for (int e = 0; e < NE; ++e) {
      float pm = 0.f; int cnt = 0;
      for (int b = 0; b < Bsz; ++b) { pm += probs[b][e]; if (top1[b] == e) cnt++; }
      aux += (pm / Bsz) * ((float)cnt / Bsz);
    }
    aux_out[0] = aux * NE;
  }
}

__global__ void convert_kernel(const float* __restrict__ src, unsigned short* __restrict__ dst,
                               int n4) {
  int i = blockIdx.x * 256 + threadIdx.x;
  if (i < n4) {
    const float4 v = ((const float4*)src)[i];
    ushort4 o = make_ushort4(f2bf(v.x), f2bf(v.y), f2bf(v.z), f2bf(v.w));
    ((ushort4*)dst)[i] = o;
  }
}

// x (B,N,D) fp32 -> x_bf16 (B,N,D) and xt_bf16 (B,D,N), fused
__global__ void transpose_kernel(const float* __restrict__ x,
                                 unsigned short* __restrict__ xbf,
                                 unsigned short* __restrict__ xtbf) {
  __shared__ unsigned short tile[64][66];  // 66: odd dword stride, conflict-free
  const int b = blockIdx.z;
  const int d0 = blockIdx.x * 64;
  const int n0 = blockIdx.y * 64;
  const int tc = threadIdx.x & 63;
  const int tr = threadIdx.x >> 6;
  const float* xb = x + (size_t)b * Nn * Dd;
#pragma unroll
  for (int i = 0; i < 16; ++i) {
    int row = tr * 16 + i;
    unsigned short v = f2bf(xb[(size_t)(n0 + row) * Dd + d0 + tc]);
    tile[row][tc] = v;
    xbf[(size_t)b * Nn * Dd + (size_t)(n0 + row) * Dd + d0 + tc] = v;
  }
  __syncthreads();
#pragma unroll
  for (int i = 0; i < 16; ++i) {
    int drow = tr * 16 + i;
    xtbf[(size_t)b * Dd * Nn + (size_t)(d0 + drow) * Nn + n0 + tc] = tile[tc][drow];
  }
}

// ---------------- expert GEMM kernels ----------------
// L1: per (tile, local-batch). e = topi[b][slot]; tok: xt(768x1024)·tok_w1[e]^T -> gelu -> inter
//                                              ch : x (1024x768)·ch_w1[e]^T  -> gelu -> inter
__global__ __launch_bounds__(256, 2) void l1_kernel(
    const unsigned short* __restrict__ xbf, const unsigned short* __restrict__ xtbf,
    const unsigned short* __restrict__ w1t, const unsigned short* __restrict__ w1c,
    const float* __restrict__ b1t, const float* __restrict__ b1c,
    const int* __restrict__ topi, unsigned short* __restrict__ inter, int slot, int b0) {
  __shared__ unsigned short sA[8192];
  __shared__ unsigned short sB[8192];
  const int y = blockIdx.y;
  const int b = b0 + y;
  const int e = topi[b * 2 + slot];
  const int tile = blockIdx.x;  // 192 tiles either way
  const unsigned short *A, *Bm;
  const float* bias;
  int K, ldc, tm, tn;
  if (e < NE_TOK) {  // token mixing: M=768(d), N=4096(hn), K=1024(n)
    A = xtbf + (size_t)b * Dd * Nn;
    Bm = w1t + (size_t)e * HN * Nn;
    bias = b1t + e * HN;
    K = Nn; ldc = HN;
    tm = tile >> 5; tn = tile & 31;            // 6 x 32
  } else {           // channel mixing: M=1024(n), N=3072(hd), K=768(d)
    A = xbf + (size_t)b * Nn * Dd;
    Bm = w1c + (size_t)(e - 4) * HD * Dd;
    bias = b1c + (e - 4) * HD;
    K = Dd; ldc = HD;
    tm = tile / 24; tn = tile - tm * 24;       // 8 x 24
  }
  unsigned short* C = inter + (size_t)y * INTER_ELEMS;
  f32x4 acc[4][4];
  gemm_core(A, Bm, K, tm, tn, sA, sB, acc);

  const int lane = threadIdx.x & 63, wave = threadIdx.x >> 6;
  const int wr = (wave >> 1) * 64, wc = (wave & 1) * 64;
  const int r0 = tm * 128 + wr + (lane >> 4) * 4;
  const int c0 = tn * 128 + wc + (lane & 15);
#pragma unroll
  for (int i = 0; i < 4; ++i)
#pragma unroll
    for (int j = 0; j < 4; ++j) {
      int col = c0 + j * 16;
      float bcol = bias[col];
#pragma unroll
      for (int r = 0; r < 4; ++r) {
        int row = r0 + i * 16 + r;
        float v = acc[i][j][r] + bcol;
        C[(size_t)row * ldc + col] = f2bf(gelu_f(v));
      }
    }
}

// L2: tok: A=tok_w2[e] (1024x4096), B^T=inter h (768x4096) -> C[n][d] directly
//     ch : A=inter g (1024x3072),  B^T=ch_w2[e] (768x3072) -> C[n][d]
// slot0: out = w*contrib (plain store); slot1: out += w*contrib
__global__ __launch_bounds__(256, 2) void l2_kernel(
    const unsigned short* __restrict__ inter,
    const unsigned short* __restrict__ w2t, const unsigned short* __restrict__ w2c,
    const float* __restrict__ b2t, const float* __restrict__ b2c,
    const int* __restrict__ topi, const float* __restrict__ topw,
    float* __restrict__ out, int slot, int b0) {
  __shared__ unsigned short sA[8192];
  __shared__ unsigned short sB[8192];
  const int y = blockIdx.y;
  const int b = b0 + y;
  const int e = topi[b * 2 + slot];
  const float wgt = topw[b * 2 + slot];
  const int tile = blockIdx.x;  // 48 tiles: 8 x 6 (M=1024, N=768)
  const int tm = tile / 6, tn = tile - tm * 6;
  const bool tok = (e < NE_TOK);
  const unsigned short* ib = inter + (size_t)y * INTER_ELEMS;
  const unsigned short *A, *Bm;
  int K;
  if (tok) { A = w2t + (size_t)e * Nn * HN; Bm = ib; K = HN; }
  else     { A = ib; Bm = w2c + (size_t)(e - 4) * Dd * HD; K = HD; }
  f32x4 acc[4][4];
  gemm_core(A, Bm, K, tm, tn, sA, sB, acc);

  float* C = out + (size_t)b * Nn * Dd;
  const int lane = threadIdx.x & 63, wave = threadIdx.x >> 6;
  const int wr = (wave >> 1) * 64, wc = (wave & 1) * 64;
  const int r0 = tm * 128 + wr + (lane >> 4) * 4;
  const int c0 = tn * 128 + wc + (lane & 15);
#pragma unroll
  for (int i = 0; i < 4; ++i)
#pragma unroll
    for (int j = 0; j < 4; ++j) {
      int col = c0 + j * 16;
#pragma unroll
      for (int r = 0; r < 4; ++r) {
        int row = r0 + i * 16 + r;
        float bias = tok ? b2t[e * Nn + row] : b2c[(e - 4) * Dd + col];
        float v = (acc[i][j][r] + bias) * wgt;
        size_t idx = (size_t)row * Dd + col;
        if (slot == 0) C[idx] = v;
        else           C[idx] += v;
      }
    }
}

// ---------------- launch ----------------
extern "C" void kernel_launch(void* const* d_in, const int* in_sizes, int n_in,
                              void* d_out, int out_size, void* d_ws, size_t ws_size,
                              hipStream_t stream) {
  const float* x       = (const float*)d_in[0];
  const float* rw      = (const float*)d_in[1];
  const float* tok_w1  = (const float*)d_in[2];
  const float* tok_b1  = (const float*)d_in[3];
  const float* tok_w2  = (const float*)d_in[4];
  const float* tok_b2  = (const float*)d_in[5];
  const float* ch_w1   = (const float*)d_in[6];
  const float* ch_b1   = (const float*)d_in[7];
  const float* ch_w2   = (const float*)d_in[8];
  const float* ch_b2   = (const float*)d_in[9];
  float* out = (float*)d_out;

  char* ws = (char*)d_ws;
  float* xmean = (float*)ws;            ws += (size_t)Bsz * Dd * 4;        // 98304
  int* topi    = (int*)ws;              ws += 256;
  float* topw  = (float*)ws;            ws += 256;
  unsigned short* xbf  = (unsigned short*)ws; ws += (size_t)Bsz * Nn * Dd * 2;  // 50.3MB
  unsigned short* xtbf = (unsigned short*)ws; ws += (size_t)Bsz * Nn * Dd * 2;  // 50.3MB
  unsigned short* w1t  = (unsigned short*)ws; ws += (size_t)NE_TOK * HN * Nn * 2;  // 33.6MB
  unsigned short* w2t  = (unsigned short*)ws; ws += (size_t)NE_TOK * Nn * HN * 2;  // 33.6MB
  unsigned short* w1c  = (unsigned short*)ws; ws += (size_t)NE_TOK * HD * Dd * 2;  // 18.9MB
  unsigned short* w2c  = (unsigned short*)ws; ws += (size_t)NE_TOK * Dd * HD * 2;  // 18.9MB
  unsigned short* inter = (unsigned short*)ws;  // CHUNK * INTER_ELEMS * 2 = 100.7MB

  mean_kernel<<<(Bsz * Dd) / 256, 256, 0, stream>>>(x, xmean);
  router_kernel<<<1, 64, 0, stream>>>(xmean, rw, topi, topw, out + (size_t)Bsz * Nn * Dd);
  convert_kernel<<<16384, 256, 0, stream>>>(tok_w1, w1t, (NE_TOK * HN * Nn) / 4);
  convert_kernel<<<16384, 256, 0, stream>>>(tok_w2, w2t, (NE_TOK * Nn * HN) / 4);
  convert_kernel<<<9216, 256, 0, stream>>>(ch_w1, w1c, (NE_TOK * HD * Dd) / 4);
  convert_kernel<<<9216, 256, 0, stream>>>(ch_w2, w2c, (NE_TOK * Dd * HD) / 4);
  transpose_kernel<<<dim3(12, 16, Bsz), 256, 0, stream>>>(x, xbf, xtbf);

  for (int slot = 0; slot < 2; ++slot)
    for (int c = 0; c < 2; ++c) {
      l1_kernel<<<dim3(192, CHUNK), 256, 0, stream>>>(xbf, xtbf, w1t, w1c, tok_b1, ch_b1,
                                                      topi, inter, slot, c * CHUNK);
      l2_kernel<<<dim3(48, CHUNK), 256, 0, stream>>>(inter, w2t, w2c, tok_b2, ch_b2,
                                                     topi, topw, out, slot, c * CHUNK);
    }
}

// Round 2
// 1687.589 us; speedup vs baseline: 1.0437x; 1.0412x over previous
//
#include <hip/hip_runtime.h>
#include <cstdint>
#include <cstddef>

#define Bsz 32
#define Nn 1024
#define Dd 768
#define NE_TOK 4
#define NE 8
#define HN 4096
#define HD 3072
#define INTER_ELEMS (768 * 4096)  /* == 1024*3072, per-pair intermediate */
#define CHUNK 16

typedef __bf16 bf16x8 __attribute__((ext_vector_type(8)));
typedef float f32x4 __attribute__((ext_vector_type(4)));
typedef unsigned int __attribute__((address_space(1))) as1_uint;
typedef unsigned int __attribute__((address_space(3))) as3_uint;

__device__ __forceinline__ unsigned short f2bf(float f) {
  union { float f; unsigned u; } c; c.f = f;
  unsigned u = c.u;
  u += 0x7fffu + ((u >> 16) & 1u);   // RNE
  return (unsigned short)(u >> 16);
}

__device__ __forceinline__ float gelu_f(float x) {
  float t = tanhf(0.7978845608028654f * (x + 0.044715f * x * x * x));
  return 0.5f * x * (1.0f + t);
}

__device__ __forceinline__ void async_cp16(const unsigned short* g, unsigned short* l) {
  __builtin_amdgcn_global_load_lds((as1_uint*)(void*)g, (as3_uint*)(void*)l, 16, 0, 0);
}

// one K-step of fragment reads + 16 MFMA (setprio-wrapped)
__device__ __forceinline__ void mfma_step(const unsigned short* pA, const unsigned short* pB,
                                          int wr, int wc, int fro, f32x4 acc[4][4]) {
  bf16x8 a[4], bb[4];
#pragma unroll
  for (int i = 0; i < 4; ++i)
    a[i] = *(const bf16x8*)(pA + (wr + i * 16) * 32 + fro);
#pragma unroll
  for (int j = 0; j < 4; ++j)
    bb[j] = *(const bf16x8*)(pB + (wc + j * 16) * 32 + fro);
  __builtin_amdgcn_s_setprio(1);
#pragma unroll
  for (int i = 0; i < 4; ++i)
#pragma unroll
    for (int j = 0; j < 4; ++j)
      acc[i][j] = __builtin_amdgcn_mfma_f32_16x16x32_bf16(a[i], bb[j], acc[i][j], 0, 0, 0);
  __builtin_amdgcn_s_setprio(0);
}

// ---------------- core 128x128 bf16 GEMM tile: C = A (M x K) * B^T (N x K) ----------------
// A, B row-major, K contiguous. 256 threads, 4 waves, each wave owns a 64x64 quadrant as
// 4x4 MFMA 16x16x32 fragments.
// 3-deep LDS pipeline with COUNTED vmcnt + raw s_barrier (T3+T4): 12 loads/wave in flight,
// each iteration waits only for its own buffer's 4 loads (vmcnt(8)), computes, then restages
// the freed slot. Loads get ~3 compute phases to complete -> HBM latency hidden.
// LDS chunk-swizzle (source-side XOR, read-side same XOR) keeps ds_read_b128 conflict-free
// (verified R1: SQ_LDS_BANK_CONFLICT -> 0).
__device__ __forceinline__ void gemm_core(const unsigned short* Ag, const unsigned short* Bg,
                                          int K, int tm, int tn,
                                          unsigned short* sA, unsigned short* sB,
                                          f32x4 acc[4][4]) {
  const int tid = threadIdx.x;
  const int wave = tid >> 6;
  const int lane = tid & 63;
  const int wr = (wave >> 1) * 64;
  const int wc = (wave & 1) * 64;

  f32x4 zero = {0.f, 0.f, 0.f, 0.f};
#pragma unroll
  for (int i = 0; i < 4; ++i)
#pragma unroll
    for (int j = 0; j < 4; ++j) acc[i][j] = zero;

  // staging: one buffer is 128 rows x 32 cols bf16 = 8KB per operand = 8 wave-calls of 1KB.
  // chunk c = q*64 + lane -> row = c>>2, chunk-in-row swizzled: cc_global = (c ^ (c>>3)) & 3
  const int q0 = wave * 2, q1 = wave * 2 + 1;
  const int c0 = q0 * 64 + lane, c1 = q1 * 64 + lane;
  const int ar0 = c0 >> 2, as0 = ((c0 ^ (c0 >> 3)) & 3) * 8;
  const int ar1 = c1 >> 2, as1 = ((c1 ^ (c1 >> 3)) & 3) * 8;
  const unsigned short* Ag0 = Ag + (size_t)(tm * 128 + ar0) * K + as0;
  const unsigned short* Ag1 = Ag + (size_t)(tm * 128 + ar1) * K + as1;
  const unsigned short* Bg0 = Bg + (size_t)(tn * 128 + ar0) * K + as0;
  const unsigned short* Bg1 = Bg + (size_t)(tn * 128 + ar1) * K + as1;
  unsigned short* sA0 = sA + q0 * 512;
  unsigned short* sA1 = sA + q1 * 512;
  unsigned short* sB0 = sB + q0 * 512;
  unsigned short* sB1 = sB + q1 * 512;

  // fragment read offset: row = wr + i*16 + (lane&15), chunk = lane>>4, same XOR swizzle
  const int swz = ((lane >> 4) ^ (lane >> 1)) & 3;
  const int fro = (lane & 15) * 32 + swz * 8;

  const int nk = K >> 5;  // >= 24 for all paths

  // prologue: stage k-steps 0,1,2 into slots 0,1,2 (12 loads per wave in flight)
#pragma unroll
  for (int p = 0; p < 3; ++p) {
    const int off = p * 4096;
    const int k = p * 32;
    async_cp16(Ag0 + k, sA0 + off);
    async_cp16(Ag1 + k, sA1 + off);
    async_cp16(Bg0 + k, sB0 + off);
    async_cp16(Bg1 + k, sB1 + off);
  }

  int o0 = 0, o1 = 4096, o2 = 8192;  // rotating slot offsets
  for (int t = 0; t < nk - 3; ++t) {
    // wait ONLY for this buffer's 4 loads (8 newer ones stay in flight across the barrier)
    asm volatile("s_waitcnt vmcnt(8)" ::: "memory");
    __builtin_amdgcn_s_barrier();
    mfma_step(sA + o0, sB + o0, wr, wc, fro, acc);
    __builtin_amdgcn_s_barrier();  // all waves done reading slot o0 -> safe to overwrite
    const int k = (t + 3) * 32;
    async_cp16(Ag0 + k, sA0 + o0);
    async_cp16(Ag1 + k, sA1 + o0);
    async_cp16(Bg0 + k, sB0 + o0);
    async_cp16(Bg1 + k, sB1 + o0);
    int tmp = o0; o0 = o1; o1 = o2; o2 = tmp;
  }
  // tail: drain 8 -> 4 -> 0, no restaging
  asm volatile("s_waitcnt vmcnt(8)" ::: "memory");
  __builtin_amdgcn_s_barrier();
  mfma_step(sA + o0, sB + o0, wr, wc, fro, acc);
  asm volatile("s_waitcnt vmcnt(4)" ::: "memory");
  __builtin_amdgcn_s_barrier();
  mfma_step(sA + o1, sB + o1, wr, wc, fro, acc);
  asm volatile("s_waitcnt vmcnt(0)" ::: "memory");
  __builtin_amdgcn_s_barrier();
  mfma_step(sA + o2, sB + o2, wr, wc, fro, acc);
}

// ---------------- prep kernels ----------------

__global__ void mean_kernel(const float* __restrict__ x, float* __restrict__ xmean) {
  int idx = blockIdx.x * 256 + threadIdx.x;  // B*D = 24576 threads
  int b = idx / Dd, d = idx - b * Dd;
  const float* p = x + (size_t)b * Nn * Dd + d;
  float s = 0.f;
#pragma unroll 8
  for (int n = 0; n < Nn; ++n) s += p[(size_t)n * Dd];
  xmean[idx] = s * (1.0f / Nn);
}

__global__ void router_kernel(const float* __restrict__ xmean, const float* __restrict__ rw,
                              int* __restrict__ topi, float* __restrict__ topw,
                              float* __restrict__ aux_out) {
  __shared__ float probs[Bsz][NE];
  __shared__ int top1[Bsz];
  int t = threadIdx.x;
  for (int p = t; p < Bsz * NE; p += 64) {
    int b = p >> 3, e = p & 7;
    const float* xm = xmean + b * Dd;
    const float* w = rw + e * Dd;
    float s = 0.f;
    for (int i = 0; i < Dd; ++i) s += xm[i] * w[i];
    probs[b][e] = s;  // logits for now
  }
  __syncthreads();
  if (t < Bsz) {
    float mx = -1e30f;
    for (int e = 0; e < NE; ++e) mx = fmaxf(mx, probs[t][e]);
    float pe[NE]; float sum = 0.f;
    for (int e = 0; e < NE; ++e) { pe[e] = expf(probs[t][e] - mx); sum += pe[e]; }
    float inv = 1.f / sum;
    for (int e = 0; e < NE; ++e) { pe[e] *= inv; probs[t][e] = pe[e]; }
    int i0 = 0;
    for (int e = 1; e < NE; ++e) if (pe[e] > pe[i0]) i0 = e;   // ties -> lowest idx (jax)
    int i1 = (i0 == 0) ? 1 : 0;
    for (int e = 0; e < NE; ++e) if (e != i0 && pe[e] > pe[i1]) i1 = e;
    float ws2 = pe[i0] + pe[i1];
    topi[t * 2] = i0; topi[t * 2 + 1] = i1;
    topw[t * 2] = pe[i0] / ws2; topw[t * 2 + 1] = pe[i1] / ws2;
    top1[t] = i0;
  }
  __syncthreads();
  if (t == 0) {
    float aux = 0.f;
    for (int e = 0; e < NE; ++e) {
      float pm = 0.f; int cnt = 0;
      for (int b = 0; b < Bsz; ++b) { pm += probs[b][e]; if (top1[b] == e) cnt++; }
      aux += (pm / Bsz) * ((float)cnt / Bsz);
    }
    aux_out[0] = aux * NE;
  }
}

__global__ void convert_kernel(const float* __restrict__ src, unsigned short* __restrict__ dst,
                               int n4) {
  int i = blockIdx.x * 256 + threadIdx.x;
  if (i < n4) {
    const float4 v = ((const float4*)src)[i];
    ushort4 o = make_ushort4(f2bf(v.x), f2bf(v.y), f2bf(v.z), f2bf(v.w));
    ((ushort4*)dst)[i] = o;
  }
}

// x (B,N,D) fp32 -> x_bf16 (B,N,D) and xt_bf16 (B,D,N), fused
__global__ void transpose_kernel(const float* __restrict__ x,
                                 unsigned short* __restrict__ xbf,
                                 unsigned short* __restrict__ xtbf) {
  __shared__ unsigned short tile[64][66];  // 66: odd dword stride, conflict-free
  const int b = blockIdx.z;
  const int d0 = blockIdx.x * 64;
  const int n0 = blockIdx.y * 64;
  const int tc = threadIdx.x & 63;
  const int tr = threadIdx.x >> 6;
  const float* xb = x + (size_t)b * Nn * Dd;
#pragma unroll
  for (int i = 0; i < 16; ++i) {
    int row = tr * 16 + i;
    unsigned short v = f2bf(xb[(size_t)(n0 + row) * Dd + d0 + tc]);
    tile[row][tc] = v;
    xbf[(size_t)b * Nn * Dd + (size_t)(n0 + row) * Dd + d0 + tc] = v;
  }
  __syncthreads();
#pragma unroll
  for (int i = 0; i < 16; ++i) {
    int drow = tr * 16 + i;
    xtbf[(size_t)b * Dd * Nn + (size_t)(d0 + drow) * Nn + n0 + tc] = tile[tc][drow];
  }
}

// ---------------- expert GEMM kernels ----------------
// L1: per (tile, local-batch). e = topi[b][slot]; tok: xt(768x1024)·tok_w1[e]^T -> gelu -> inter
//                                              ch : x (1024x768)·ch_w1[e]^T  -> gelu -> inter
__global__ __launch_bounds__(256, 3) void l1_kernel(
    const unsigned short* __restrict__ xbf, const unsigned short* __restrict__ xtbf,
    const unsigned short* __restrict__ w1t, const unsigned short* __restrict__ w1c,
    const float* __restrict__ b1t, const float* __restrict__ b1c,
    const int* __restrict__ topi, unsigned short* __restrict__ inter, int slot, int b0) {
  __shared__ unsigned short sA[3 * 4096];
  __shared__ unsigned short sB[3 * 4096];
  // XCD-chunked bijective swizzle: 3072 % 8 == 0; each XCD gets 384 consecutive work items
  const int orig = blockIdx.y * 192 + blockIdx.x;
  const int swzid = (orig & 7) * 384 + (orig >> 3);
  const int y = swzid / 192;
  const int tile = swzid - y * 192;
  const int b = b0 + y;
  const int e = topi[b * 2 + slot];
  const unsigned short *A, *Bm;
  const float* bias;
  int K, ldc, tm, tn;
  if (e < NE_TOK) {  // token mixing: M=768(d), N=4096(hn), K=1024(n)
    A = xtbf + (size_t)b * Dd * Nn;
    Bm = w1t + (size_t)e * HN * Nn;
    bias = b1t + e * HN;
    K = Nn; ldc = HN;
    tm = tile >> 5; tn = tile & 31;            // 6 x 32
  } else {           // channel mixing: M=1024(n), N=3072(hd), K=768(d)
    A = xbf + (size_t)b * Nn * Dd;
    Bm = w1c + (size_t)(e - 4) * HD * Dd;
    bias = b1c + (e - 4) * HD;
    K = Dd; ldc = HD;
    tm = tile / 24; tn = tile - tm * 24;       // 8 x 24
  }
  unsigned short* C = inter + (size_t)y * INTER_ELEMS;
  f32x4 acc[4][4];
  gemm_core(A, Bm, K, tm, tn, sA, sB, acc);

  const int lane = threadIdx.x & 63, wave = threadIdx.x >> 6;
  const int wr = (wave >> 1) * 64, wc = (wave & 1) * 64;
  const int r0 = tm * 128 + wr + (lane >> 4) * 4;
  const int c0 = tn * 128 + wc + (lane & 15);
#pragma unroll
  for (int i = 0; i < 4; ++i)
#pragma unroll
    for (int j = 0; j < 4; ++j) {
      int col = c0 + j * 16;
      float bcol = bias[col];
#pragma unroll
      for (int r = 0; r < 4; ++r) {
        int row = r0 + i * 16 + r;
        float v = acc[i][j][r] + bcol;
        C[(size_t)row * ldc + col] = f2bf(gelu_f(v));
      }
    }
}

// L2: tok: A=tok_w2[e] (1024x4096), B^T=inter h (768x4096) -> C[n][d] directly
//     ch : A=inter g (1024x3072),  B^T=ch_w2[e] (768x3072) -> C[n][d]
// slot0: out = w*contrib (plain store); slot1: out += w*contrib
__global__ __launch_bounds__(256, 3) void l2_kernel(
    const unsigned short* __restrict__ inter,
    const unsigned short* __restrict__ w2t, const unsigned short* __restrict__ w2c,
    const float* __restrict__ b2t, const float* __restrict__ b2c,
    const int* __restrict__ topi, const float* __restrict__ topw,
    float* __restrict__ out, int slot, int b0) {
  __shared__ unsigned short sA[3 * 4096];
  __shared__ unsigned short sB[3 * 4096];
  // XCD-chunked bijective swizzle: 768 % 8 == 0; each XCD gets 96 consecutive work items
  const int orig = blockIdx.y * 48 + blockIdx.x;
  const int swzid = (orig & 7) * 96 + (orig >> 3);
  const int y = swzid / 48;
  const int tile = swzid - y * 48;
  const int b = b0 + y;
  const int e = topi[b * 2 + slot];
  const float wgt = topw[b * 2 + slot];
  const int tm = tile / 6, tn = tile - tm * 6;  // 8 x 6 (M=1024, N=768)
  const bool tok = (e < NE_TOK);
  const unsigned short* ib = inter + (size_t)y * INTER_ELEMS;
  const unsigned short *A, *Bm;
  int K;
  if (tok) { A = w2t + (size_t)e * Nn * HN; Bm = ib; K = HN; }
  else     { A = ib; Bm = w2c + (size_t)(e - 4) * Dd * HD; K = HD; }
  f32x4 acc[4][4];
  gemm_core(A, Bm, K, tm, tn, sA, sB, acc);

  float* C = out + (size_t)b * Nn * Dd;
  const int lane = threadIdx.x & 63, wave = threadIdx.x >> 6;
  const int wr = (wave >> 1) * 64, wc = (wave & 1) * 64;
  const int r0 = tm * 128 + wr + (lane >> 4) * 4;
  const int c0 = tn * 128 + wc + (lane & 15);
#pragma unroll
  for (int i = 0; i < 4; ++i)
#pragma unroll
    for (int j = 0; j < 4; ++j) {
      int col = c0 + j * 16;
#pragma unroll
      for (int r = 0; r < 4; ++r) {
        int row = r0 + i * 16 + r;
        float bias = tok ? b2t[e * Nn + row] : b2c[(e - 4) * Dd + col];
        float v = (acc[i][j][r] + bias) * wgt;
        size_t idx = (size_t)row * Dd + col;
        if (slot == 0) C[idx] = v;
        else           C[idx] += v;
      }
    }
}

// ---------------- launch ----------------
extern "C" void kernel_launch(void* const* d_in, const int* in_sizes, int n_in,
                              void* d_out, int out_size, void* d_ws, size_t ws_size,
                              hipStream_t stream) {
  const float* x       = (const float*)d_in[0];
  const float* rw      = (const float*)d_in[1];
  const float* tok_w1  = (const float*)d_in[2];
  const float* tok_b1  = (const float*)d_in[3];
  const float* tok_w2  = (const float*)d_in[4];
  const float* tok_b2  = (const float*)d_in[5];
  const float* ch_w1   = (const float*)d_in[6];
  const float* ch_b1   = (const float*)d_in[7];
  const float* ch_w2   = (const float*)d_in[8];
  const float* ch_b2   = (const float*)d_in[9];
  float* out = (float*)d_out;

  char* ws = (char*)d_ws;
  float* xmean = (float*)ws;            ws += (size_t)Bsz * Dd * 4;        // 98304
  int* topi    = (int*)ws;              ws += 256;
  float* topw  = (float*)ws;            ws += 256;
  unsigned short* xbf  = (unsigned short*)ws; ws += (size_t)Bsz * Nn * Dd * 2;  // 50.3MB
  unsigned short* xtbf = (unsigned short*)ws; ws += (size_t)Bsz * Nn * Dd * 2;  // 50.3MB
  unsigned short* w1t  = (unsigned short*)ws; ws += (size_t)NE_TOK * HN * Nn * 2;  // 33.6MB
  unsigned short* w2t  = (unsigned short*)ws; ws += (size_t)NE_TOK * Nn * HN * 2;  // 33.6MB
  unsigned short* w1c  = (unsigned short*)ws; ws += (size_t)NE_TOK * HD * Dd * 2;  // 18.9MB
  unsigned short* w2c  = (unsigned short*)ws; ws += (size_t)NE_TOK * Dd * HD * 2;  // 18.9MB
  unsigned short* inter = (unsigned short*)ws;  // CHUNK * INTER_ELEMS * 2 = 100.7MB

  mean_kernel<<<(Bsz * Dd) / 256, 256, 0, stream>>>(x, xmean);
  router_kernel<<<1, 64, 0, stream>>>(xmean, rw, topi, topw, out + (size_t)Bsz * Nn * Dd);
  convert_kernel<<<16384, 256, 0, stream>>>(tok_w1, w1t, (NE_TOK * HN * Nn) / 4);
  convert_kernel<<<16384, 256, 0, stream>>>(tok_w2, w2t, (NE_TOK * Nn * HN) / 4);
  convert_kernel<<<9216, 256, 0, stream>>>(ch_w1, w1c, (NE_TOK * HD * Dd) / 4);
  convert_kernel<<<9216, 256, 0, stream>>>(ch_w2, w2c, (NE_TOK * Dd * HD) / 4);
  transpose_kernel<<<dim3(12, 16, Bsz), 256, 0, stream>>>(x, xbf, xtbf);

  for (int slot = 0; slot < 2; ++slot)
    for (int c = 0; c < 2; ++c) {
      l1_kernel<<<dim3(192, CHUNK), 256, 0, stream>>>(xbf, xtbf, w1t, w1c, tok_b1, ch_b1,
                                                      topi, inter, slot, c * CHUNK);
      l2_kernel<<<dim3(48, CHUNK), 256, 0, stream>>>(inter, w2t, w2c, tok_b2, ch_b2,
                                                     topi, topw, out, slot, c * CHUNK);
    }
}